// Round 2
// baseline (195.243 us; speedup 1.0000x reference)
//
#include <hip/hip_runtime.h>
#include <hip/hip_bf16.h>

// out[n,c] = y[n,c] + 0.5 * ratio * S_raw[labels[n], c]
// S_raw[k,c] = sum_a cov[k,a]*(W[c,a]-W[k,a])^2
//            = P[k,:]·Q[c,:] + term3[k],  P=[cov | cov*W], Q=[W^2 | -2W]  (bf16 MFMA)
// Pipeline (3 dispatches):
//   stats (label scan in-block + per-class sums [MLP-2 gather] + EstimatorCV
//          + bf16 pack + term3)
//   -> smm (1024x1024x1536 bf16 GEMM, dbuf LDS, 1 barrier/chunk, dist-2 prefetch;
//           S pre-scaled by 0.5*ratio)
//   -> out (gather-add, 131 MB HBM floor, exact-cover grid, no bounds check).

constexpr int Nn = 16384;
constexpr int Aa = 768;
constexpr int Cc = 1000;
constexpr int Cp = 1024;   // padded class count
constexpr int Kk = 1536;   // 2*Aa
constexpr int SLOTS = 64;  // max rows/class (lambda=16.4; P(>64) ~ 1e-20)

using f32x4  = __attribute__((ext_vector_type(4))) float;
using bf16x8 = __attribute__((ext_vector_type(8))) short;

static __device__ inline unsigned short f2bf(float x) {
    __hip_bfloat16 h = __float2bfloat16(x);
    return *reinterpret_cast<unsigned short*>(&h);
}

// One block per (padded) class, 192 threads; thread t owns a = 4t..4t+3 (float4).
// Row discovery: every block scans the 64 KB label array (L2-resident) and
// appends matching rows to an LDS list — replaces a memset+scatter dispatch pair.
__global__ __launch_bounds__(192) void stats_kernel(
    const float4* __restrict__ f4, const int* __restrict__ labels,
    const float* __restrict__ count_in,
    const float4* __restrict__ mean4, const float4* __restrict__ cov4,
    const float4* __restrict__ W4,
    unsigned short* __restrict__ P, unsigned short* __restrict__ Q,
    float* __restrict__ term3)
{
    int c = blockIdx.x;
    int t = threadIdx.x;                 // 0..191
    int a = t * 4;
    size_t pq = (size_t)c * Kk;
    if (c >= Cc) {                       // padded classes: zero P/Q rows
        ushort4 z = {0, 0, 0, 0};
        *(ushort4*)&P[pq + a] = z; *(ushort4*)&P[pq + Aa + a] = z;
        *(ushort4*)&Q[pq + a] = z; *(ushort4*)&Q[pq + Aa + a] = z;
        return;                          // term3[c>=Cc] never read (smm guards k<Cc)
    }
    __shared__ int list[SLOTS];
    __shared__ int s_cnt;
    __shared__ float red[3];
    if (t == 0) s_cnt = 0;
    __syncthreads();
    // scan labels as int4: 4096 vectors, stride 192 -> 21-22 L2 loads/thread
    const int4* lab4 = (const int4*)labels;
    for (int j = t; j < Nn / 4; j += 192) {
        int4 v = lab4[j];
        if (v.x == c) { int p = atomicAdd(&s_cnt, 1); if (p < SLOTS) list[p] = 4 * j;     }
        if (v.y == c) { int p = atomicAdd(&s_cnt, 1); if (p < SLOTS) list[p] = 4 * j + 1; }
        if (v.z == c) { int p = atomicAdd(&s_cnt, 1); if (p < SLOTS) list[p] = 4 * j + 2; }
        if (v.w == c) { int p = atomicAdd(&s_cnt, 1); if (p < SLOTS) list[p] = 4 * j + 3; }
    }
    __syncthreads();
    int cntRaw = s_cnt;                  // full count (matches cursor semantics)
    int cnt = min(cntRaw, SLOTS);

    // depth-2 software pipeline: two independent HBM row-loads in flight
    float sf[4] = {0, 0, 0, 0}, sf2[4] = {0, 0, 0, 0};
    int idx0 = (cnt > 0) ? list[0] : 0;
    int idx1 = (cnt > 1) ? list[1] : 0;
    int r = 0;
    for (; r + 1 < cnt; r += 2) {
        float4 v0 = f4[(size_t)idx0 * 192 + t];
        float4 v1 = f4[(size_t)idx1 * 192 + t];
        if (r + 2 < cnt) idx0 = list[r + 2];
        if (r + 3 < cnt) idx1 = list[r + 3];
        sf[0] += v0.x; sf2[0] += v0.x * v0.x;
        sf[1] += v0.y; sf2[1] += v0.y * v0.y;
        sf[2] += v0.z; sf2[2] += v0.z * v0.z;
        sf[3] += v0.w; sf2[3] += v0.w * v0.w;
        sf[0] += v1.x; sf2[0] += v1.x * v1.x;
        sf[1] += v1.y; sf2[1] += v1.y * v1.y;
        sf[2] += v1.z; sf2[2] += v1.z * v1.z;
        sf[3] += v1.w; sf2[3] += v1.w * v1.w;
    }
    if (r < cnt) {                       // odd-count tail (idx0 holds list[r])
        float4 v = f4[(size_t)idx0 * 192 + t];
        sf[0] += v.x; sf2[0] += v.x * v.x;
        sf[1] += v.y; sf2[1] += v.y * v.y;
        sf[2] += v.z; sf2[2] += v.z * v.z;
        sf[3] += v.w; sf2[3] += v.w * v.w;
    }
    float cntf = (float)cntRaw;
    float amt = fmaxf(cntf, 1.0f);
    float denom = cntf + count_in[c];
    float w = denom > 0.0f ? cntf / fmaxf(denom, 1.0f) : 0.0f;
    float4 mn = mean4[(size_t)c * 192 + t];
    float4 cv = cov4[(size_t)c * 192 + t];
    float4 wv = W4[(size_t)c * 192 + t];
    float mnA[4] = {mn.x, mn.y, mn.z, mn.w};
    float cvA[4] = {cv.x, cv.y, cv.z, cv.w};
    float wvA[4] = {wv.x, wv.y, wv.z, wv.w};
    ushort4 p0, p1, q0, q1;
    unsigned short* p0a = (unsigned short*)&p0;
    unsigned short* p1a = (unsigned short*)&p1;
    unsigned short* q0a = (unsigned short*)&q0;
    unsigned short* q1a = (unsigned short*)&q1;
    float t3 = 0.0f;
    #pragma unroll
    for (int j = 0; j < 4; ++j) {
        float ave = sf[j] / amt;
        float var = (sf2[j] - 2.0f * ave * sf[j] + cntf * ave * ave) / amt;
        float d = mnA[j] - ave;
        float cov = cvA[j] * (1.0f - w) + var * w + w * (1.0f - w) * d * d;
        float wj = wvA[j];
        p0a[j] = f2bf(cov);
        p1a[j] = f2bf(cov * wj);
        q0a[j] = f2bf(wj * wj);
        q1a[j] = f2bf(-2.0f * wj);
        t3 = fmaf(cov, wj * wj, t3);
    }
    *(ushort4*)&P[pq + a]      = p0;
    *(ushort4*)&P[pq + Aa + a] = p1;
    *(ushort4*)&Q[pq + a]      = q0;
    *(ushort4*)&Q[pq + Aa + a] = q1;
    // term3 via in-block reduction (3 waves) -> no global atomic, no zeroing needed
    #pragma unroll
    for (int s = 32; s > 0; s >>= 1) t3 += __shfl_down(t3, s, 64);
    if ((t & 63) == 0) red[t >> 6] = t3;
    __syncthreads();
    if (t == 0) term3[c] = red[0] + red[1] + red[2];
}

// S[k,c] = 0.5 * ratio * (P[k,:]·Q[c,:] + term3[k])   (0.5 folded here)
// 64x64 tile, 4 waves (2x2), 2x2 MFMA 16x16x32 each. K-chunk 64.
// Double-buffered LDS: ONE barrier per chunk; distance-2 register prefetch.
// LDS row stride 72 shorts (144 B): conflict-free b128 frag reads, 16B-aligned.
__global__ __launch_bounds__(256) void smm_kernel(
    const unsigned short* __restrict__ P, const unsigned short* __restrict__ Q,
    const float* __restrict__ term3, const float* __restrict__ ratio,
    float* __restrict__ S)
{
    constexpr int SST = 72;                 // shorts per LDS row (64 data + 8 pad)
    constexpr int BUF = 64 * SST;           // 9216 shorts per buffer
    __shared__ unsigned short sP[2 * BUF];  // 36 KB total with sQ
    __shared__ unsigned short sQ[2 * BUF];
    int t = threadIdx.x;
    int w = t >> 6, l = t & 63;
    int quad = l >> 4, l16 = l & 15;
    int wr = w >> 1, wc = w & 1;
    int kbase = blockIdx.y * 64;            // P rows (class k)
    int cbase = blockIdx.x * 64;            // Q rows (class c)

    int row0 = t >> 3, row1 = row0 + 32, g = t & 7;
    const unsigned short* pSrc0 = P + (size_t)(kbase + row0) * Kk + g * 8;
    const unsigned short* pSrc1 = P + (size_t)(kbase + row1) * Kk + g * 8;
    const unsigned short* qSrc0 = Q + (size_t)(cbase + row0) * Kk + g * 8;
    const unsigned short* qSrc1 = Q + (size_t)(cbase + row1) * Kk + g * 8;
    int dOff0 = row0 * SST + g * 8;
    int dOff1 = row1 * SST + g * 8;

    // chunk 0 -> buf 0, then issue chunk 1 prefetch
    uint4 pv0 = *(const uint4*)pSrc0;
    uint4 pv1 = *(const uint4*)pSrc1;
    uint4 qv0 = *(const uint4*)qSrc0;
    uint4 qv1 = *(const uint4*)qSrc1;
    *(uint4*)&sP[dOff0] = pv0;
    *(uint4*)&sP[dOff1] = pv1;
    *(uint4*)&sQ[dOff0] = qv0;
    *(uint4*)&sQ[dOff1] = qv1;
    pv0 = *(const uint4*)(pSrc0 + 64);
    pv1 = *(const uint4*)(pSrc1 + 64);
    qv0 = *(const uint4*)(qSrc0 + 64);
    qv1 = *(const uint4*)(qSrc1 + 64);
    __syncthreads();

    f32x4 acc[2][2] = {};
    constexpr int NCH = Kk / 64;            // 24 chunks
    for (int it = 0; it < NCH; ++it) {
        int cur = it & 1;
        const unsigned short* bP = &sP[cur * BUF];
        const unsigned short* bQ = &sQ[cur * BUF];
        #pragma unroll
        for (int kstep = 0; kstep < 2; ++kstep) {
            bf16x8 aF[2], bF[2];
            #pragma unroll
            for (int mt = 0; mt < 2; ++mt)
                aF[mt] = *(const bf16x8*)&bP[(wr * 32 + mt * 16 + l16) * SST
                                             + kstep * 32 + quad * 8];
            #pragma unroll
            for (int nt = 0; nt < 2; ++nt)
                bF[nt] = *(const bf16x8*)&bQ[(wc * 32 + nt * 16 + l16) * SST
                                             + kstep * 32 + quad * 8];
            #pragma unroll
            for (int mt = 0; mt < 2; ++mt)
                #pragma unroll
                for (int nt = 0; nt < 2; ++nt)
                    acc[mt][nt] = __builtin_amdgcn_mfma_f32_16x16x32_bf16(
                        aF[mt], bF[nt], acc[mt][nt], 0, 0, 0);
        }
        if (it + 1 < NCH) {                 // write chunk it+1 into the other buffer
            int nb = (cur ^ 1) * BUF;
            *(uint4*)&sP[nb + dOff0] = pv0;
            *(uint4*)&sP[nb + dOff1] = pv1;
            *(uint4*)&sQ[nb + dOff0] = qv0;
            *(uint4*)&sQ[nb + dOff1] = qv1;
            if (it + 2 < NCH) {             // issue chunk it+2 (lands next iter)
                int k0 = (it + 2) * 64;
                pv0 = *(const uint4*)(pSrc0 + k0);
                pv1 = *(const uint4*)(pSrc1 + k0);
                qv0 = *(const uint4*)(qSrc0 + k0);
                qv1 = *(const uint4*)(qSrc1 + k0);
            }
        }
        __syncthreads();
    }
    float r = 0.5f * ratio[0];              // fold the 0.5 from the epilogue add
    #pragma unroll
    for (int mt = 0; mt < 2; ++mt) {
        int krow0 = kbase + wr * 32 + mt * 16 + quad * 4;
        #pragma unroll
        for (int nt = 0; nt < 2; ++nt) {
            int ccol = cbase + wc * 32 + nt * 16 + l16;
            if (ccol < Cc) {
                #pragma unroll
                for (int reg = 0; reg < 4; ++reg) {
                    int k = krow0 + reg;
                    if (k < Cc)
                        S[(size_t)k * Cc + ccol] = r * (acc[mt][nt][reg] + term3[k]);
                }
            }
        }
    }
}

// 131 MB touch-once traffic: nontemporal y/out keeps L2 free for the S gather.
// Grid covers total4 exactly (8000 * 512 == 16384 * 250): no bounds checks.
__global__ __launch_bounds__(256) void out_kernel(
    const f32x4* __restrict__ y4, const int* __restrict__ labels,
    const float* __restrict__ S, f32x4* __restrict__ out4)
{
    unsigned i0 = blockIdx.x * 512u + threadIdx.x;
    unsigned i1 = i0 + 256u;
    unsigned n0 = i0 / 250u, c40 = i0 - n0 * 250u;
    unsigned n1 = i1 / 250u, c41 = i1 - n1 * 250u;
    int k0 = labels[n0];
    int k1 = labels[n1];
    f32x4 yv0 = __builtin_nontemporal_load(&y4[i0]);
    f32x4 yv1 = __builtin_nontemporal_load(&y4[i1]);
    f32x4 sv0 = ((const f32x4*)(S + (size_t)k0 * Cc))[c40];
    f32x4 sv1 = ((const f32x4*)(S + (size_t)k1 * Cc))[c41];
    f32x4 o0 = yv0 + sv0;                  // 0.5*ratio already folded into S
    f32x4 o1 = yv1 + sv1;
    __builtin_nontemporal_store(o0, &out4[i0]);
    __builtin_nontemporal_store(o1, &out4[i1]);
}

extern "C" void kernel_launch(void* const* d_in, const int* in_sizes, int n_in,
                              void* d_out, int out_size, void* d_ws, size_t ws_size,
                              hipStream_t stream) {
    const float* y        = (const float*)d_in[0];
    const float* features = (const float*)d_in[1];
    const float* fc_w     = (const float*)d_in[2];
    const int*   labels   = (const int*)d_in[3];
    const float* count_in = (const float*)d_in[4];
    const float* mean_in  = (const float*)d_in[5];
    const float* cov_in   = (const float*)d_in[6];
    const float* ratio    = (const float*)d_in[7];

    char* base = (char*)d_ws;
    float* term3 = (float*)base;                           // 4 KB
    unsigned short* P = (unsigned short*)(base + 4096);    // 3 MB
    unsigned short* Q = P + (size_t)Cp * Kk;               // 3 MB
    float* S = (float*)(Q + (size_t)Cp * Kk);              // 4 MB

    stats_kernel<<<Cp, 192, 0, stream>>>(
        (const float4*)features, labels, count_in,
        (const float4*)mean_in, (const float4*)cov_in, (const float4*)fc_w,
        P, Q, term3);

    dim3 gS(Cp / 64, Cp / 64);   // 16 x 16 = 256 blocks
    smm_kernel<<<gS, 256, 0, stream>>>(P, Q, term3, ratio, S);

    out_kernel<<<8000, 256, 0, stream>>>(
        (const f32x4*)y, labels, S, (f32x4*)d_out);
}

// Round 3
// 193.238 us; speedup vs baseline: 1.0104x; 1.0104x over previous
//
#include <hip/hip_runtime.h>
#include <hip/hip_bf16.h>

// out[n,c] = y[n,c] + 0.5 * ratio * S_raw[labels[n], c]
// S_raw[k,c] = sum_a cov[k,a]*(W[c,a]-W[k,a])^2
//            = P[k,:]·Q[c,:] + term3[k],  P=[cov | cov*W], Q=[W^2 | -2W]  (bf16 MFMA)
// Pipeline (3 dispatches):
//   stats (label scan in-block + per-class sums [MLP-4 gather, hoisted CV loads]
//          + EstimatorCV + bf16 pack + term3)
//   -> smm (1024x1024x1536 bf16 GEMM, dbuf LDS, 1 barrier/chunk, dist-2 prefetch;
//           S pre-scaled by 0.5*ratio)
//   -> out (gather-add, 131 MB HBM floor, exact-cover grid, no bounds check).

constexpr int Nn = 16384;
constexpr int Aa = 768;
constexpr int Cc = 1000;
constexpr int Cp = 1024;   // padded class count
constexpr int Kk = 1536;   // 2*Aa
constexpr int SLOTS = 64;  // max rows/class (lambda=16.4; P(>64) ~ 1e-20)

using f32x4  = __attribute__((ext_vector_type(4))) float;
using bf16x8 = __attribute__((ext_vector_type(8))) short;

static __device__ inline unsigned short f2bf(float x) {
    __hip_bfloat16 h = __float2bfloat16(x);
    return *reinterpret_cast<unsigned short*>(&h);
}

// One block per (padded) class, 192 threads; thread t owns a = 4t..4t+3 (float4).
// Row discovery: every block scans the 64 KB label array (L2-resident) and
// appends matching rows to an LDS list — replaces a memset+scatter dispatch pair.
// Gather loop runs a depth-4 software pipeline: 4 independent HBM row loads in
// flight per thread (768/block), so the straggler class (cnt~45) pays ~12 HBM
// round-trips instead of 45. CV inputs (mean/cov/W/count) are issued BEFORE the
// gather so their latency hides under it.
__global__ __launch_bounds__(192) void stats_kernel(
    const float4* __restrict__ f4, const int* __restrict__ labels,
    const float* __restrict__ count_in,
    const float4* __restrict__ mean4, const float4* __restrict__ cov4,
    const float4* __restrict__ W4,
    unsigned short* __restrict__ P, unsigned short* __restrict__ Q,
    float* __restrict__ term3)
{
    int c = blockIdx.x;
    int t = threadIdx.x;                 // 0..191
    int a = t * 4;
    size_t pq = (size_t)c * Kk;
    if (c >= Cc) {                       // padded classes: zero P/Q rows
        ushort4 z = {0, 0, 0, 0};
        *(ushort4*)&P[pq + a] = z; *(ushort4*)&P[pq + Aa + a] = z;
        *(ushort4*)&Q[pq + a] = z; *(ushort4*)&Q[pq + Aa + a] = z;
        return;                          // term3[c>=Cc] never read (smm guards k<Cc)
    }
    __shared__ int list[SLOTS];
    __shared__ int s_cnt;
    __shared__ float red[3];
    if (t == 0) s_cnt = 0;
    __syncthreads();
    // issue CV-input loads first: independent HBM traffic overlapping the scan+gather
    float4 mn = mean4[(size_t)c * 192 + t];
    float4 cv = cov4[(size_t)c * 192 + t];
    float4 wv = W4[(size_t)c * 192 + t];
    float countc = count_in[c];
    // scan labels as int4: 4096 vectors, stride 192 -> 21-22 L2 loads/thread
    const int4* lab4 = (const int4*)labels;
    for (int j = t; j < Nn / 4; j += 192) {
        int4 v = lab4[j];
        if (v.x == c) { int p = atomicAdd(&s_cnt, 1); if (p < SLOTS) list[p] = 4 * j;     }
        if (v.y == c) { int p = atomicAdd(&s_cnt, 1); if (p < SLOTS) list[p] = 4 * j + 1; }
        if (v.z == c) { int p = atomicAdd(&s_cnt, 1); if (p < SLOTS) list[p] = 4 * j + 2; }
        if (v.w == c) { int p = atomicAdd(&s_cnt, 1); if (p < SLOTS) list[p] = 4 * j + 3; }
    }
    __syncthreads();
    int cntRaw = s_cnt;                  // full count (matches cursor semantics)
    int cnt = min(cntRaw, SLOTS);

    // depth-4 software pipeline: four independent HBM row-loads in flight
    float sf[4] = {0, 0, 0, 0}, sf2[4] = {0, 0, 0, 0};
    int i0 = (cnt > 0) ? list[0] : 0;
    int i1 = (cnt > 1) ? list[1] : 0;
    int i2 = (cnt > 2) ? list[2] : 0;
    int i3 = (cnt > 3) ? list[3] : 0;
    int r = 0;
    for (; r + 3 < cnt; r += 4) {
        float4 v0 = f4[(size_t)i0 * 192 + t];
        float4 v1 = f4[(size_t)i1 * 192 + t];
        float4 v2 = f4[(size_t)i2 * 192 + t];
        float4 v3 = f4[(size_t)i3 * 192 + t];
        if (r + 4 < cnt) i0 = list[r + 4];
        if (r + 5 < cnt) i1 = list[r + 5];
        if (r + 6 < cnt) i2 = list[r + 6];
        if (r + 7 < cnt) i3 = list[r + 7];
        sf[0] += v0.x; sf2[0] += v0.x * v0.x;
        sf[1] += v0.y; sf2[1] += v0.y * v0.y;
        sf[2] += v0.z; sf2[2] += v0.z * v0.z;
        sf[3] += v0.w; sf2[3] += v0.w * v0.w;
        sf[0] += v1.x; sf2[0] += v1.x * v1.x;
        sf[1] += v1.y; sf2[1] += v1.y * v1.y;
        sf[2] += v1.z; sf2[2] += v1.z * v1.z;
        sf[3] += v1.w; sf2[3] += v1.w * v1.w;
        sf[0] += v2.x; sf2[0] += v2.x * v2.x;
        sf[1] += v2.y; sf2[1] += v2.y * v2.y;
        sf[2] += v2.z; sf2[2] += v2.z * v2.z;
        sf[3] += v2.w; sf2[3] += v2.w * v2.w;
        sf[0] += v3.x; sf2[0] += v3.x * v3.x;
        sf[1] += v3.y; sf2[1] += v3.y * v3.y;
        sf[2] += v3.z; sf2[2] += v3.z * v3.z;
        sf[3] += v3.w; sf2[3] += v3.w * v3.w;
    }
    for (; r < cnt; ++r) {               // tail 0..3 rows (list reads hit LDS)
        float4 v = f4[(size_t)list[r] * 192 + t];
        sf[0] += v.x; sf2[0] += v.x * v.x;
        sf[1] += v.y; sf2[1] += v.y * v.y;
        sf[2] += v.z; sf2[2] += v.z * v.z;
        sf[3] += v.w; sf2[3] += v.w * v.w;
    }
    float cntf = (float)cntRaw;
    float amt = fmaxf(cntf, 1.0f);
    float denom = cntf + countc;
    float w = denom > 0.0f ? cntf / fmaxf(denom, 1.0f) : 0.0f;
    float mnA[4] = {mn.x, mn.y, mn.z, mn.w};
    float cvA[4] = {cv.x, cv.y, cv.z, cv.w};
    float wvA[4] = {wv.x, wv.y, wv.z, wv.w};
    ushort4 p0, p1, q0, q1;
    unsigned short* p0a = (unsigned short*)&p0;
    unsigned short* p1a = (unsigned short*)&p1;
    unsigned short* q0a = (unsigned short*)&q0;
    unsigned short* q1a = (unsigned short*)&q1;
    float t3 = 0.0f;
    #pragma unroll
    for (int j = 0; j < 4; ++j) {
        float ave = sf[j] / amt;
        float var = (sf2[j] - 2.0f * ave * sf[j] + cntf * ave * ave) / amt;
        float d = mnA[j] - ave;
        float cov = cvA[j] * (1.0f - w) + var * w + w * (1.0f - w) * d * d;
        float wj = wvA[j];
        p0a[j] = f2bf(cov);
        p1a[j] = f2bf(cov * wj);
        q0a[j] = f2bf(wj * wj);
        q1a[j] = f2bf(-2.0f * wj);
        t3 = fmaf(cov, wj * wj, t3);
    }
    *(ushort4*)&P[pq + a]      = p0;
    *(ushort4*)&P[pq + Aa + a] = p1;
    *(ushort4*)&Q[pq + a]      = q0;
    *(ushort4*)&Q[pq + Aa + a] = q1;
    // term3 via in-block reduction (3 waves) -> no global atomic, no zeroing needed
    #pragma unroll
    for (int s = 32; s > 0; s >>= 1) t3 += __shfl_down(t3, s, 64);
    if ((t & 63) == 0) red[t >> 6] = t3;
    __syncthreads();
    if (t == 0) term3[c] = red[0] + red[1] + red[2];
}

// S[k,c] = 0.5 * ratio * (P[k,:]·Q[c,:] + term3[k])   (0.5 folded here)
// 64x64 tile, 4 waves (2x2), 2x2 MFMA 16x16x32 each. K-chunk 64.
// Double-buffered LDS: ONE barrier per chunk; distance-2 register prefetch.
// LDS row stride 72 shorts (144 B): conflict-free b128 frag reads, 16B-aligned.
__global__ __launch_bounds__(256) void smm_kernel(
    const unsigned short* __restrict__ P, const unsigned short* __restrict__ Q,
    const float* __restrict__ term3, const float* __restrict__ ratio,
    float* __restrict__ S)
{
    constexpr int SST = 72;                 // shorts per LDS row (64 data + 8 pad)
    constexpr int BUF = 64 * SST;           // 9216 shorts per buffer
    __shared__ unsigned short sP[2 * BUF];  // 36 KB total with sQ
    __shared__ unsigned short sQ[2 * BUF];
    int t = threadIdx.x;
    int w = t >> 6, l = t & 63;
    int quad = l >> 4, l16 = l & 15;
    int wr = w >> 1, wc = w & 1;
    int kbase = blockIdx.y * 64;            // P rows (class k)
    int cbase = blockIdx.x * 64;            // Q rows (class c)

    int row0 = t >> 3, row1 = row0 + 32, g = t & 7;
    const unsigned short* pSrc0 = P + (size_t)(kbase + row0) * Kk + g * 8;
    const unsigned short* pSrc1 = P + (size_t)(kbase + row1) * Kk + g * 8;
    const unsigned short* qSrc0 = Q + (size_t)(cbase + row0) * Kk + g * 8;
    const unsigned short* qSrc1 = Q + (size_t)(cbase + row1) * Kk + g * 8;
    int dOff0 = row0 * SST + g * 8;
    int dOff1 = row1 * SST + g * 8;

    // chunk 0 -> buf 0, then issue chunk 1 prefetch
    uint4 pv0 = *(const uint4*)pSrc0;
    uint4 pv1 = *(const uint4*)pSrc1;
    uint4 qv0 = *(const uint4*)qSrc0;
    uint4 qv1 = *(const uint4*)qSrc1;
    *(uint4*)&sP[dOff0] = pv0;
    *(uint4*)&sP[dOff1] = pv1;
    *(uint4*)&sQ[dOff0] = qv0;
    *(uint4*)&sQ[dOff1] = qv1;
    pv0 = *(const uint4*)(pSrc0 + 64);
    pv1 = *(const uint4*)(pSrc1 + 64);
    qv0 = *(const uint4*)(qSrc0 + 64);
    qv1 = *(const uint4*)(qSrc1 + 64);
    __syncthreads();

    f32x4 acc[2][2] = {};
    constexpr int NCH = Kk / 64;            // 24 chunks
    for (int it = 0; it < NCH; ++it) {
        int cur = it & 1;
        const unsigned short* bP = &sP[cur * BUF];
        const unsigned short* bQ = &sQ[cur * BUF];
        #pragma unroll
        for (int kstep = 0; kstep < 2; ++kstep) {
            bf16x8 aF[2], bF[2];
            #pragma unroll
            for (int mt = 0; mt < 2; ++mt)
                aF[mt] = *(const bf16x8*)&bP[(wr * 32 + mt * 16 + l16) * SST
                                             + kstep * 32 + quad * 8];
            #pragma unroll
            for (int nt = 0; nt < 2; ++nt)
                bF[nt] = *(const bf16x8*)&bQ[(wc * 32 + nt * 16 + l16) * SST
                                             + kstep * 32 + quad * 8];
            #pragma unroll
            for (int mt = 0; mt < 2; ++mt)
                #pragma unroll
                for (int nt = 0; nt < 2; ++nt)
                    acc[mt][nt] = __builtin_amdgcn_mfma_f32_16x16x32_bf16(
                        aF[mt], bF[nt], acc[mt][nt], 0, 0, 0);
        }
        if (it + 1 < NCH) {                 // write chunk it+1 into the other buffer
            int nb = (cur ^ 1) * BUF;
            *(uint4*)&sP[nb + dOff0] = pv0;
            *(uint4*)&sP[nb + dOff1] = pv1;
            *(uint4*)&sQ[nb + dOff0] = qv0;
            *(uint4*)&sQ[nb + dOff1] = qv1;
            if (it + 2 < NCH) {             // issue chunk it+2 (lands next iter)
                int k0 = (it + 2) * 64;
                pv0 = *(const uint4*)(pSrc0 + k0);
                pv1 = *(const uint4*)(pSrc1 + k0);
                qv0 = *(const uint4*)(qSrc0 + k0);
                qv1 = *(const uint4*)(qSrc1 + k0);
            }
        }
        __syncthreads();
    }
    float r = 0.5f * ratio[0];              // fold the 0.5 from the epilogue add
    #pragma unroll
    for (int mt = 0; mt < 2; ++mt) {
        int krow0 = kbase + wr * 32 + mt * 16 + quad * 4;
        #pragma unroll
        for (int nt = 0; nt < 2; ++nt) {
            int ccol = cbase + wc * 32 + nt * 16 + l16;
            if (ccol < Cc) {
                #pragma unroll
                for (int reg = 0; reg < 4; ++reg) {
                    int k = krow0 + reg;
                    if (k < Cc)
                        S[(size_t)k * Cc + ccol] = r * (acc[mt][nt][reg] + term3[k]);
                }
            }
        }
    }
}

// 131 MB touch-once traffic: nontemporal y/out keeps L2 free for the S gather.
// Grid covers total4 exactly (8000 * 512 == 16384 * 250): no bounds checks.
__global__ __launch_bounds__(256) void out_kernel(
    const f32x4* __restrict__ y4, const int* __restrict__ labels,
    const float* __restrict__ S, f32x4* __restrict__ out4)
{
    unsigned i0 = blockIdx.x * 512u + threadIdx.x;
    unsigned i1 = i0 + 256u;
    unsigned n0 = i0 / 250u, c40 = i0 - n0 * 250u;
    unsigned n1 = i1 / 250u, c41 = i1 - n1 * 250u;
    int k0 = labels[n0];
    int k1 = labels[n1];
    f32x4 yv0 = __builtin_nontemporal_load(&y4[i0]);
    f32x4 yv1 = __builtin_nontemporal_load(&y4[i1]);
    f32x4 sv0 = ((const f32x4*)(S + (size_t)k0 * Cc))[c40];
    f32x4 sv1 = ((const f32x4*)(S + (size_t)k1 * Cc))[c41];
    f32x4 o0 = yv0 + sv0;                  // 0.5*ratio already folded into S
    f32x4 o1 = yv1 + sv1;
    __builtin_nontemporal_store(o0, &out4[i0]);
    __builtin_nontemporal_store(o1, &out4[i1]);
}

extern "C" void kernel_launch(void* const* d_in, const int* in_sizes, int n_in,
                              void* d_out, int out_size, void* d_ws, size_t ws_size,
                              hipStream_t stream) {
    const float* y        = (const float*)d_in[0];
    const float* features = (const float*)d_in[1];
    const float* fc_w     = (const float*)d_in[2];
    const int*   labels   = (const int*)d_in[3];
    const float* count_in = (const float*)d_in[4];
    const float* mean_in  = (const float*)d_in[5];
    const float* cov_in   = (const float*)d_in[6];
    const float* ratio    = (const float*)d_in[7];

    char* base = (char*)d_ws;
    float* term3 = (float*)base;                           // 4 KB
    unsigned short* P = (unsigned short*)(base + 4096);    // 3 MB
    unsigned short* Q = P + (size_t)Cp * Kk;               // 3 MB
    float* S = (float*)(Q + (size_t)Cp * Kk);              // 4 MB

    stats_kernel<<<Cp, 192, 0, stream>>>(
        (const float4*)features, labels, count_in,
        (const float4*)mean_in, (const float4*)cov_in, (const float4*)fc_w,
        P, Q, term3);

    dim3 gS(Cp / 64, Cp / 64);   // 16 x 16 = 256 blocks
    smm_kernel<<<gS, 256, 0, stream>>>(P, Q, term3, ratio, S);

    out_kernel<<<8000, 256, 0, stream>>>(
        (const f32x4*)y, labels, S, (f32x4*)d_out);
}